// Round 14
// baseline (51.162 us; speedup 1.0000x reference)
//
#include <hip/hip_runtime.h>
#include <hip/hip_bf16.h>

#define NROWS 8192
#define DIM   128
#define NPAIR (NROWS / 2)
#define CSPLIT 32                        // col chunks -> partial[row][32]
#define COLS_PER_CS (NROWS / CSPLIT)     // 256 cols per chunk
#define NTILES (COLS_PER_CS / 16)        // 16 col-tiles per chunk
#define MREP 2                           // 16-row tiles per wave -> 32 rows
#define ROWS_PER_BLOCK 128               // 4 waves * 32 rows

typedef __attribute__((ext_vector_type(8))) short bf16x8;
typedef __attribute__((ext_vector_type(4))) float f32x4;

__device__ inline float exp2_fast(float x) {
#if __has_builtin(__builtin_amdgcn_exp2f)
    return __builtin_amdgcn_exp2f(x);
#else
    return exp2f(x);
#endif
}

__device__ inline unsigned short f2bf(float f) {
    unsigned int u = __float_as_uint(f);
    unsigned int r = (u + 0x7fffu + ((u >> 16) & 1u)) >> 16;
    return (unsigned short)r;
}

// exp(d/128 + 1) = e * exp2(d * SCL); SCL baked into the packed A array,
// e folded into the partial write.
#define SCL_F 0.0112710550069450f      // log2(e)/128
#define E1_F  2.7182818284590452f

// Kernel 1: pack X (f32) into MFMA-fragment order (verified: absmax 0.0).
// Fragment f = tile*4+g holds, at [lane*8+e], element (row = tile*16 +
// (lane&15), k = g*32 + (lane>>4)*8 + e). A wave-load P[f*64+lane] is
// 64 lanes x 16B fully contiguous. Pa scaled by SCL, Pb unscaled.
__global__ __launch_bounds__(256) void k_pack(const float* __restrict__ X,
                                              unsigned short* __restrict__ Pa,
                                              unsigned short* __restrict__ Pb) {
    int id = blockIdx.x * 256 + threadIdx.x;     // 0 .. 262143
    float4 v = reinterpret_cast<const float4*>(X)[id];
    int r  = id >> 5;                 // row 0..8191
    int k0 = (id & 31) * 4;           // 0,4,...,124
    int tile = r >> 4;
    int g    = k0 >> 5;               // 0..3
    int lhi  = (k0 >> 3) & 3;         // 0..3
    int e0   = k0 & 7;                // 0 or 4
    size_t base = ((size_t)(tile * 4 + g) * 64 + lhi * 16 + (r & 15)) * 8 + e0;
    ushort4 oa, ob;
    oa.x = f2bf(v.x * SCL_F); oa.y = f2bf(v.y * SCL_F);
    oa.z = f2bf(v.z * SCL_F); oa.w = f2bf(v.w * SCL_F);
    ob.x = f2bf(v.x); ob.y = f2bf(v.y); ob.z = f2bf(v.z); ob.w = f2bf(v.w);
    *reinterpret_cast<ushort4*>(Pa + base) = oa;
    *reinterpret_cast<ushort4*>(Pb + base) = ob;
}

#define MFMA16(A, B, D) __builtin_amdgcn_mfma_f32_16x16x32_bf16(A, B, D, 0, 0, 0)

// Kernel 2: partial[row][cs] = e * sum over 256-col chunk cs of exp2(SCL*dot).
// SOFTWARE-PIPELINED (the R14 change): MFMA results of iter t (p0/p1) are
// exp'd AFTER issuing iter t+1's b-loads -- the exp2+accumulate block is
// the independent work that hides L2 load latency and MFMA-result latency.
// R13's serial chain (load->wait->mfma->exp with nothing between) is why
// VALUBusy sat at 10-18% for 13 rounds.
__global__ __launch_bounds__(256)
void k_rowsum(const unsigned short* __restrict__ Pa,
              const unsigned short* __restrict__ Pb,
              float* __restrict__ partial) {
    const int wave = threadIdx.x >> 6;
    const int lane = threadIdx.x & 63;
    const int l15  = lane & 15;
    const int lhi  = lane >> 4;   // 0..3
    const int rowbase = blockIdx.x * ROWS_PER_BLOCK + wave * (MREP * 16);
    const int rb0 = rowbase >> 4;            // first 16-row tile of this wave
    const int cs  = blockIdx.y;

    const bf16x8* PA = reinterpret_cast<const bf16x8*>(Pa);
    const bf16x8* PB = reinterpret_cast<const bf16x8*>(Pb);

    // A fragments: 2 row-tiles x 4 k-groups = 32 VGPRs, coalesced, pinned.
    bf16x8 a00 = PA[(size_t)(rb0 * 4 + 0) * 64 + lane];
    bf16x8 a01 = PA[(size_t)(rb0 * 4 + 1) * 64 + lane];
    bf16x8 a02 = PA[(size_t)(rb0 * 4 + 2) * 64 + lane];
    bf16x8 a03 = PA[(size_t)(rb0 * 4 + 3) * 64 + lane];
    bf16x8 a10 = PA[(size_t)(rb0 * 4 + 4) * 64 + lane];
    bf16x8 a11 = PA[(size_t)(rb0 * 4 + 5) * 64 + lane];
    bf16x8 a12 = PA[(size_t)(rb0 * 4 + 6) * 64 + lane];
    bf16x8 a13 = PA[(size_t)(rb0 * 4 + 7) * 64 + lane];
    asm volatile("" : "+v"(a00), "+v"(a01), "+v"(a02), "+v"(a03));
    asm volatile("" : "+v"(a10), "+v"(a11), "+v"(a12), "+v"(a13));

    f32x4 esum0 = {0.f, 0.f, 0.f, 0.f};
    f32x4 esum1 = {0.f, 0.f, 0.f, 0.f};

    size_t tb = (size_t)cs * NTILES * 256 + lane;   // 256 frags16 per tile

    // ---- prologue: iter 0 loads + MFMAs (no exp yet) ----
    f32x4 p0 = {0.f, 0.f, 0.f, 0.f};
    f32x4 p1 = {0.f, 0.f, 0.f, 0.f};
    {
        bf16x8 b0 = PB[tb];
        bf16x8 b1 = PB[tb + 64];
        bf16x8 b2 = PB[tb + 128];
        bf16x8 b3 = PB[tb + 192];
        tb += 256;
        p0 = MFMA16(a00, b0, p0); p1 = MFMA16(a10, b0, p1);
        p0 = MFMA16(a01, b1, p0); p1 = MFMA16(a11, b1, p1);
        p0 = MFMA16(a02, b2, p0); p1 = MFMA16(a12, b2, p1);
        p0 = MFMA16(a03, b3, p0); p1 = MFMA16(a13, b3, p1);
    }

    // ---- steady state: load(t) || exp(t-1) -> mfma(t) ----
    for (int ct = 1; ct < NTILES; ++ct) {
        bf16x8 b0 = PB[tb];
        bf16x8 b1 = PB[tb + 64];
        bf16x8 b2 = PB[tb + 128];
        bf16x8 b3 = PB[tb + 192];
        tb += 256;

        // independent of the loads above: hides their latency
        esum0[0] += exp2_fast(p0[0]); esum0[1] += exp2_fast(p0[1]);
        esum0[2] += exp2_fast(p0[2]); esum0[3] += exp2_fast(p0[3]);
        esum1[0] += exp2_fast(p1[0]); esum1[1] += exp2_fast(p1[1]);
        esum1[2] += exp2_fast(p1[2]); esum1[3] += exp2_fast(p1[3]);

        f32x4 q0 = {0.f, 0.f, 0.f, 0.f};
        f32x4 q1 = {0.f, 0.f, 0.f, 0.f};
        q0 = MFMA16(a00, b0, q0); q1 = MFMA16(a10, b0, q1);
        q0 = MFMA16(a01, b1, q0); q1 = MFMA16(a11, b1, q1);
        q0 = MFMA16(a02, b2, q0); q1 = MFMA16(a12, b2, q1);
        q0 = MFMA16(a03, b3, q0); q1 = MFMA16(a13, b3, q1);
        p0 = q0; p1 = q1;     // register rotate (renamed, zero cost)
    }

    // ---- epilogue: exp of the last tile ----
    esum0[0] += exp2_fast(p0[0]); esum0[1] += exp2_fast(p0[1]);
    esum0[2] += exp2_fast(p0[2]); esum0[3] += exp2_fast(p0[3]);
    esum1[0] += exp2_fast(p1[0]); esum1[1] += exp2_fast(p1[1]);
    esum1[2] += exp2_fast(p1[2]); esum1[3] += exp2_fast(p1[3]);

    // Reduce the 16 column-lanes (varying l15); one slot per row.
#pragma unroll
    for (int m = 0; m < MREP; ++m) {
#pragma unroll
        for (int j = 0; j < 4; ++j) {
            float v = (m == 0) ? esum0[j] : esum1[j];
            v += __shfl_xor(v, 1, 64);
            v += __shfl_xor(v, 2, 64);
            v += __shfl_xor(v, 4, 64);
            v += __shfl_xor(v, 8, 64);
            if (l15 == 0) {
                int row = rowbase + m * 16 + lhi * 4 + j;
                partial[(size_t)row * CSPLIT + cs] = v * E1_F;
            }
        }
    }
}

// Kernel 3: per-pair exact f32 2x2 block + D_pos + J^2, block-reduced.
__global__ __launch_bounds__(256) void k_loss1(const float* __restrict__ X,
                                               const float* __restrict__ partial,
                                               float* __restrict__ lpart) {
    int p = blockIdx.x * 256 + threadIdx.x;   // 0..4095
    const float4* a = reinterpret_cast<const float4*>(X + (size_t)(2 * p) * DIM);
    const float4* b = reinterpret_cast<const float4*>(X + (size_t)(2 * p + 1) * DIM);
    float d00 = 0.f, d01 = 0.f, d11 = 0.f;
#pragma unroll 8
    for (int i = 0; i < DIM / 4; ++i) {
        float4 av = a[i], bv = b[i];
        d00 += av.x * av.x + av.y * av.y + av.z * av.z + av.w * av.w;
        d01 += av.x * bv.x + av.y * bv.y + av.z * bv.z + av.w * bv.w;
        d11 += bv.x * bv.x + bv.y * bv.y + bv.z * bv.z + bv.w * bv.w;
    }
    float D01 = d01 * (1.0f / DIM);
    float blocksum = __expf(d00 * (1.0f / DIM) + 1.0f)
                   + 2.0f * __expf(D01 + 1.0f)
                   + __expf(d11 * (1.0f / DIM) + 1.0f);

    const float4* pp = reinterpret_cast<const float4*>(partial + (size_t)(2 * p) * CSPLIT);
    float S = 0.0f;
#pragma unroll
    for (int i = 0; i < 2 * CSPLIT / 4; ++i) {
        float4 v = pp[i];
        S += v.x + v.y + v.z + v.w;
    }
    S -= blocksum;
    float J = logf(1e-8f + S) - D01;
    float t = fmaxf(J, 0.0f);
    float acc = t * t;

    __shared__ float red[4];
    float v = acc;
#pragma unroll
    for (int off = 32; off >= 1; off >>= 1) v += __shfl_down(v, off, 64);
    if ((threadIdx.x & 63) == 0) red[threadIdx.x >> 6] = v;
    __syncthreads();
    if (threadIdx.x == 0)
        lpart[blockIdx.x] = red[0] + red[1] + red[2] + red[3];
}

// Kernel 4: final 16-element sum -> loss.
__global__ __launch_bounds__(64) void k_final(const float* __restrict__ lpart,
                                              float* __restrict__ out) {
    float v = (threadIdx.x < 16) ? lpart[threadIdx.x] : 0.0f;
#pragma unroll
    for (int off = 8; off >= 1; off >>= 1) v += __shfl_down(v, off, 64);
    if (threadIdx.x == 0) out[0] = v * (1.0f / (2.0f * NPAIR));
}

extern "C" void kernel_launch(void* const* d_in, const int* in_sizes, int n_in,
                              void* d_out, int out_size, void* d_ws, size_t ws_size,
                              hipStream_t stream) {
    const float* X = (const float*)d_in[0];
    float* out = (float*)d_out;

    unsigned short* Pa = (unsigned short*)d_ws;                        // 2 MB
    unsigned short* Pb = Pa + (size_t)NROWS * DIM;                     // 2 MB
    float* partial = (float*)(Pb + (size_t)NROWS * DIM);               // 1 MB
    float* lpart = partial + (size_t)NROWS * CSPLIT;                   // 64 B

    k_pack<<<dim3((NROWS * DIM / 4) / 256), dim3(256), 0, stream>>>(X, Pa, Pb);
    k_rowsum<<<dim3(NROWS / ROWS_PER_BLOCK, CSPLIT), dim3(256), 0, stream>>>(Pa, Pb, partial);
    k_loss1<<<dim3(NPAIR / 256), dim3(256), 0, stream>>>(X, partial, lpart);
    k_final<<<dim3(1), dim3(64), 0, stream>>>(lpart, out);
}

// Round 15
// 47.666 us; speedup vs baseline: 1.0733x; 1.0733x over previous
//
#include <hip/hip_runtime.h>
#include <hip/hip_bf16.h>

#define NROWS 8192
#define DIM   128
#define NPAIR (NROWS / 2)
#define CSPLIT 64                        // col chunks -> partial[row][64]
#define COLS_PER_CS (NROWS / CSPLIT)     // 128 cols per chunk
#define NTILES (COLS_PER_CS / 16)        // 8 col-tiles per chunk
#define MREP 4                           // 16-row tiles per wave -> 64 rows
#define ROWS_PER_BLOCK 256               // 4 waves * 64 rows

typedef __attribute__((ext_vector_type(8))) short bf16x8;
typedef __attribute__((ext_vector_type(4))) float f32x4;

__device__ inline float exp2_fast(float x) {
#if __has_builtin(__builtin_amdgcn_exp2f)
    return __builtin_amdgcn_exp2f(x);
#else
    return exp2f(x);
#endif
}

__device__ inline unsigned short f2bf(float f) {
    unsigned int u = __float_as_uint(f);
    unsigned int r = (u + 0x7fffu + ((u >> 16) & 1u)) >> 16;
    return (unsigned short)r;
}

// exp(d/128 + 1) = e * exp2(d * SCL); SCL baked into the packed A array,
// e folded into the partial write.
#define SCL_F 0.0112710550069450f      // log2(e)/128
#define E1_F  2.7182818284590452f

// Kernel 1: pack X (f32) into MFMA-fragment order (verified: absmax 0.0).
// Fragment f = tile*4+g holds, at [lane*8+e], element (row = tile*16 +
// (lane&15), k = g*32 + (lane>>4)*8 + e). A wave-load P[f*64+lane] is
// 64 lanes x 16B fully contiguous. Pa scaled by SCL, Pb unscaled.
__global__ __launch_bounds__(256) void k_pack(const float* __restrict__ X,
                                              unsigned short* __restrict__ Pa,
                                              unsigned short* __restrict__ Pb) {
    int id = blockIdx.x * 256 + threadIdx.x;     // 0 .. 262143
    float4 v = reinterpret_cast<const float4*>(X)[id];
    int r  = id >> 5;                 // row 0..8191
    int k0 = (id & 31) * 4;           // 0,4,...,124
    int tile = r >> 4;
    int g    = k0 >> 5;               // 0..3
    int lhi  = (k0 >> 3) & 3;         // 0..3
    int e0   = k0 & 7;                // 0 or 4
    size_t base = ((size_t)(tile * 4 + g) * 64 + lhi * 16 + (r & 15)) * 8 + e0;
    ushort4 oa, ob;
    oa.x = f2bf(v.x * SCL_F); oa.y = f2bf(v.y * SCL_F);
    oa.z = f2bf(v.z * SCL_F); oa.w = f2bf(v.w * SCL_F);
    ob.x = f2bf(v.x); ob.y = f2bf(v.y); ob.z = f2bf(v.z); ob.w = f2bf(v.w);
    *reinterpret_cast<ushort4*>(Pa + base) = oa;
    *reinterpret_cast<ushort4*>(Pb + base) = ob;
}

#define MFMA16(A, B, D) __builtin_amdgcn_mfma_f32_16x16x32_bf16(A, B, D, 0, 0, 0)

// Kernel 2: partial[row][cs] = e * sum over 128-col chunk cs of exp2(SCL*dot).
// MREP=4 (64 rows/wave): halves the B-bytes-per-output -> halves the
// L1-return-port floor (13.6 -> 6.8 us). The 64 A-fragment regs live in
// the AGPR partition ("+a" pins; gfx950 MFMA reads A from AGPR natively,
// ISA §10) -- R11 proved this keeps the arch-VGPR partition spill-free
// where "+v" (R10) and unpinned (R3/R5) both collapsed.
// Structure otherwise = R13 (cleanest codegen): coalesced 1KB loads,
// no LDS, no barriers, simple rolled loop.
__global__ __launch_bounds__(256)
void k_rowsum(const unsigned short* __restrict__ Pa,
              const unsigned short* __restrict__ Pb,
              float* __restrict__ partial) {
    const int wave = threadIdx.x >> 6;
    const int lane = threadIdx.x & 63;
    const int l15  = lane & 15;
    const int lhi  = lane >> 4;   // 0..3
    const int rowbase = blockIdx.x * ROWS_PER_BLOCK + wave * (MREP * 16);
    const int rb0 = rowbase >> 4;            // first 16-row tile of this wave
    const int cs  = blockIdx.y;

    const bf16x8* PA = reinterpret_cast<const bf16x8*>(Pa);
    const bf16x8* PB = reinterpret_cast<const bf16x8*>(Pb);

    // A fragments: 4 row-tiles x 4 k-groups = 64 regs -> AGPR partition.
    bf16x8 a00 = PA[(size_t)(rb0 * 4 +  0) * 64 + lane];
    bf16x8 a01 = PA[(size_t)(rb0 * 4 +  1) * 64 + lane];
    bf16x8 a02 = PA[(size_t)(rb0 * 4 +  2) * 64 + lane];
    bf16x8 a03 = PA[(size_t)(rb0 * 4 +  3) * 64 + lane];
    bf16x8 a10 = PA[(size_t)(rb0 * 4 +  4) * 64 + lane];
    bf16x8 a11 = PA[(size_t)(rb0 * 4 +  5) * 64 + lane];
    bf16x8 a12 = PA[(size_t)(rb0 * 4 +  6) * 64 + lane];
    bf16x8 a13 = PA[(size_t)(rb0 * 4 +  7) * 64 + lane];
    bf16x8 a20 = PA[(size_t)(rb0 * 4 +  8) * 64 + lane];
    bf16x8 a21 = PA[(size_t)(rb0 * 4 +  9) * 64 + lane];
    bf16x8 a22 = PA[(size_t)(rb0 * 4 + 10) * 64 + lane];
    bf16x8 a23 = PA[(size_t)(rb0 * 4 + 11) * 64 + lane];
    bf16x8 a30 = PA[(size_t)(rb0 * 4 + 12) * 64 + lane];
    bf16x8 a31 = PA[(size_t)(rb0 * 4 + 13) * 64 + lane];
    bf16x8 a32 = PA[(size_t)(rb0 * 4 + 14) * 64 + lane];
    bf16x8 a33 = PA[(size_t)(rb0 * 4 + 15) * 64 + lane];
    asm volatile("" : "+a"(a00), "+a"(a01), "+a"(a02), "+a"(a03));
    asm volatile("" : "+a"(a10), "+a"(a11), "+a"(a12), "+a"(a13));
    asm volatile("" : "+a"(a20), "+a"(a21), "+a"(a22), "+a"(a23));
    asm volatile("" : "+a"(a30), "+a"(a31), "+a"(a32), "+a"(a33));

    f32x4 es0 = {0.f,0.f,0.f,0.f}, es1 = {0.f,0.f,0.f,0.f};
    f32x4 es2 = {0.f,0.f,0.f,0.f}, es3 = {0.f,0.f,0.f,0.f};

    size_t tb = (size_t)cs * NTILES * 256 + lane;   // 256 frags16 per tile

    for (int ct = 0; ct < NTILES; ++ct) {
        bf16x8 b0 = PB[tb];
        bf16x8 b1 = PB[tb + 64];
        bf16x8 b2 = PB[tb + 128];
        bf16x8 b3 = PB[tb + 192];
        tb += 256;

        f32x4 d0 = {0.f,0.f,0.f,0.f}, d1 = {0.f,0.f,0.f,0.f};
        f32x4 d2 = {0.f,0.f,0.f,0.f}, d3 = {0.f,0.f,0.f,0.f};
        d0 = MFMA16(a00, b0, d0); d1 = MFMA16(a10, b0, d1);
        d2 = MFMA16(a20, b0, d2); d3 = MFMA16(a30, b0, d3);
        d0 = MFMA16(a01, b1, d0); d1 = MFMA16(a11, b1, d1);
        d2 = MFMA16(a21, b1, d2); d3 = MFMA16(a31, b1, d3);
        d0 = MFMA16(a02, b2, d0); d1 = MFMA16(a12, b2, d1);
        d2 = MFMA16(a22, b2, d2); d3 = MFMA16(a32, b2, d3);
        d0 = MFMA16(a03, b3, d0); d1 = MFMA16(a13, b3, d1);
        d2 = MFMA16(a23, b3, d2); d3 = MFMA16(a33, b3, d3);

        es0[0] += exp2_fast(d0[0]); es0[1] += exp2_fast(d0[1]);
        es0[2] += exp2_fast(d0[2]); es0[3] += exp2_fast(d0[3]);
        es1[0] += exp2_fast(d1[0]); es1[1] += exp2_fast(d1[1]);
        es1[2] += exp2_fast(d1[2]); es1[3] += exp2_fast(d1[3]);
        es2[0] += exp2_fast(d2[0]); es2[1] += exp2_fast(d2[1]);
        es2[2] += exp2_fast(d2[2]); es2[3] += exp2_fast(d2[3]);
        es3[0] += exp2_fast(d3[0]); es3[1] += exp2_fast(d3[1]);
        es3[2] += exp2_fast(d3[2]); es3[3] += exp2_fast(d3[3]);
    }

    // Reduce the 16 column-lanes (varying l15); one slot per row.
#pragma unroll
    for (int m = 0; m < MREP; ++m) {
#pragma unroll
        for (int j = 0; j < 4; ++j) {
            float v = (m == 0) ? es0[j] : (m == 1) ? es1[j]
                    : (m == 2) ? es2[j] : es3[j];
            v += __shfl_xor(v, 1, 64);
            v += __shfl_xor(v, 2, 64);
            v += __shfl_xor(v, 4, 64);
            v += __shfl_xor(v, 8, 64);
            if (l15 == 0) {
                int row = rowbase + m * 16 + lhi * 4 + j;
                partial[(size_t)row * CSPLIT + cs] = v * E1_F;
            }
        }
    }
}

// Kernel 3: per-pair exact f32 2x2 block + D_pos + J^2, block-reduced.
__global__ __launch_bounds__(256) void k_loss1(const float* __restrict__ X,
                                               const float* __restrict__ partial,
                                               float* __restrict__ lpart) {
    int p = blockIdx.x * 256 + threadIdx.x;   // 0..4095
    const float4* a = reinterpret_cast<const float4*>(X + (size_t)(2 * p) * DIM);
    const float4* b = reinterpret_cast<const float4*>(X + (size_t)(2 * p + 1) * DIM);
    float d00 = 0.f, d01 = 0.f, d11 = 0.f;
#pragma unroll 8
    for (int i = 0; i < DIM / 4; ++i) {
        float4 av = a[i], bv = b[i];
        d00 += av.x * av.x + av.y * av.y + av.z * av.z + av.w * av.w;
        d01 += av.x * bv.x + av.y * bv.y + av.z * bv.z + av.w * bv.w;
        d11 += bv.x * bv.x + bv.y * bv.y + bv.z * bv.z + bv.w * bv.w;
    }
    float D01 = d01 * (1.0f / DIM);
    float blocksum = __expf(d00 * (1.0f / DIM) + 1.0f)
                   + 2.0f * __expf(D01 + 1.0f)
                   + __expf(d11 * (1.0f / DIM) + 1.0f);

    const float4* pp = reinterpret_cast<const float4*>(partial + (size_t)(2 * p) * CSPLIT);
    float S = 0.0f;
#pragma unroll
    for (int i = 0; i < 2 * CSPLIT / 4; ++i) {
        float4 v = pp[i];
        S += v.x + v.y + v.z + v.w;
    }
    S -= blocksum;
    float J = logf(1e-8f + S) - D01;
    float t = fmaxf(J, 0.0f);
    float acc = t * t;

    __shared__ float red[4];
    float v = acc;
#pragma unroll
    for (int off = 32; off >= 1; off >>= 1) v += __shfl_down(v, off, 64);
    if ((threadIdx.x & 63) == 0) red[threadIdx.x >> 6] = v;
    __syncthreads();
    if (threadIdx.x == 0)
        lpart[blockIdx.x] = red[0] + red[1] + red[2] + red[3];
}

// Kernel 4: final 16-element sum -> loss.
__global__ __launch_bounds__(64) void k_final(const float* __restrict__ lpart,
                                              float* __restrict__ out) {
    float v = (threadIdx.x < 16) ? lpart[threadIdx.x] : 0.0f;
#pragma unroll
    for (int off = 8; off >= 1; off >>= 1) v += __shfl_down(v, off, 64);
    if (threadIdx.x == 0) out[0] = v * (1.0f / (2.0f * NPAIR));
}

extern "C" void kernel_launch(void* const* d_in, const int* in_sizes, int n_in,
                              void* d_out, int out_size, void* d_ws, size_t ws_size,
                              hipStream_t stream) {
    const float* X = (const float*)d_in[0];
    float* out = (float*)d_out;

    unsigned short* Pa = (unsigned short*)d_ws;                        // 2 MB
    unsigned short* Pb = Pa + (size_t)NROWS * DIM;                     // 2 MB
    float* partial = (float*)(Pb + (size_t)NROWS * DIM);               // 2 MB
    float* lpart = partial + (size_t)NROWS * CSPLIT;                   // 64 B

    k_pack<<<dim3((NROWS * DIM / 4) / 256), dim3(256), 0, stream>>>(X, Pa, Pb);
    k_rowsum<<<dim3(NROWS / ROWS_PER_BLOCK, CSPLIT), dim3(256), 0, stream>>>(Pa, Pb, partial);
    k_loss1<<<dim3(NPAIR / 256), dim3(256), 0, stream>>>(X, partial, lpart);
    k_final<<<dim3(1), dim3(64), 0, stream>>>(lpart, out);
}